// Round 4
// baseline (337.223 us; speedup 1.0000x reference)
//
#include <hip/hip_runtime.h>
#include <cstdint>
#include <cstddef>

// ---------- types ----------
typedef __attribute__((ext_vector_type(8)))  __bf16 bf16x8;
typedef __attribute__((ext_vector_type(4)))  __bf16 bf16x4;
typedef __attribute__((ext_vector_type(4)))  float  f32x4;
typedef __attribute__((ext_vector_type(16))) float  f32x16;
typedef __attribute__((ext_vector_type(2)))  uint32_t u32x2;
typedef __attribute__((ext_vector_type(4)))  uint32_t u32x4;

#define MFMA_BF16(a, b, c) __builtin_amdgcn_mfma_f32_16x16x32_bf16((a), (b), (c), 0, 0, 0)
#define MFMA32(a, b, c)    __builtin_amdgcn_mfma_f32_32x32x16_bf16((a), (b), (c), 0, 0, 0)

// async global->LDS, 16B per lane. LDS dest must be wave-uniform base + lane*16.
__device__ __forceinline__ void gload_lds16(const __bf16* src, __bf16* lds_dst) {
    __builtin_amdgcn_global_load_lds(
        (const __attribute__((address_space(1))) void*)(const_cast<__bf16*>(src)),
        (__attribute__((address_space(3))) void*)(lds_dst), 16, 0, 0);
}

__device__ __forceinline__ uint32_t pack2(float a, float b) {
    uint16_t ua = __builtin_bit_cast(uint16_t, (__bf16)a);
    uint16_t ub = __builtin_bit_cast(uint16_t, (__bf16)b);
    return (uint32_t)ua | ((uint32_t)ub << 16);
}

// ---------- fp32 -> bf16 convert ----------
__global__ __launch_bounds__(256) void cvt_kernel(const float* __restrict__ src,
                                                  __bf16* __restrict__ dst) {
    int i = blockIdx.x * 256 + threadIdx.x;
    float4 v = reinterpret_cast<const float4*>(src)[i];
    bf16x4 o;
    o[0] = (__bf16)v.x; o[1] = (__bf16)v.y; o[2] = (__bf16)v.z; o[3] = (__bf16)v.w;
    reinterpret_cast<bf16x4*>(dst)[i] = o;
}

// ---------- RMSNorm (row = 1024 fp32) -> bf16 ----------
__global__ __launch_bounds__(256) void rmsnorm_kernel(const float* __restrict__ x,
                                                      const float* __restrict__ g,
                                                      __bf16* __restrict__ out) {
    const int row = blockIdx.x;
    const int t = threadIdx.x;
    float4 v = reinterpret_cast<const float4*>(x + (size_t)row * 1024)[t];
    float ss = v.x * v.x + v.y * v.y + v.z * v.z + v.w * v.w;
#pragma unroll
    for (int m = 1; m < 64; m <<= 1) ss += __shfl_xor(ss, m);
    __shared__ float sred[4];
    if ((t & 63) == 0) sred[t >> 6] = ss;
    __syncthreads();
    float tot = sred[0] + sred[1] + sred[2] + sred[3];
    float rs = rsqrtf(tot * (1.0f / 1024.0f) + 1.1920928955078125e-07f);
    float4 gv = reinterpret_cast<const float4*>(g)[t];
    bf16x4 o;
    o[0] = (__bf16)(v.x * rs * gv.x);
    o[1] = (__bf16)(v.y * rs * gv.y);
    o[2] = (__bf16)(v.z * rs * gv.z);
    o[3] = (__bf16)(v.w * rs * gv.w);
    *reinterpret_cast<bf16x4*>(out + (size_t)row * 1024 + t * 4) = o;
}

// ---------- pipelined NT GEMM (big-K path): C[m,n] = sum_k A[m,k]*B[n,k] ----------
// BM=256, BN=128, BK=64; 512 thr = 8 waves (4x2); per-wave 64x64 = 2x2 frags of
// 32x32x16. 3 LDS buffers, depth-2 prefetch, counted vmcnt(6) (T3+T4).
// MODE 0: out bf16. MODE 2: FFN1+SwiGLU fused (B rows pre-permuted via srow).
template <int MODE>
__global__ __launch_bounds__(512, 2) void gemm_pipe(const __bf16* __restrict__ A, int lda,
                                                    const __bf16* __restrict__ B, int ldb,
                                                    __bf16* __restrict__ outb,
                                                    int K, int ldo) {
    __shared__ __attribute__((aligned(16))) __bf16 As[3][256 * 64];
    __shared__ __attribute__((aligned(16))) __bf16 Bs[3][128 * 64];
    const int t = threadIdx.x;
    const int lane = t & 63;
    const int wid = t >> 6;
    const int l31 = lane & 31;
    const int hi = lane >> 5;
    const int bm = blockIdx.x, bn = blockIdx.y;
    const int wm = (wid >> 1) * 64;     // 0,64,128,192
    const int wn = (wid & 1) * 64;      // 0,64

    // staging pointers: per-thread, advance 64 elements per K-tile
    const __bf16* aptr[4];
    const __bf16* bptr[2];
#pragma unroll
    for (int i = 0; i < 4; ++i) {
        int L = i * 512 + t; int r = L >> 3; int c = (L & 7) ^ (r & 7);
        aptr[i] = A + (size_t)(bm * 256 + r) * lda + c * 8;
    }
#pragma unroll
    for (int i = 0; i < 2; ++i) {
        int L = i * 512 + t; int r = L >> 3; int c = (L & 7) ^ (r & 7);
        int rb = bn * 128 + r;
        int srow = (MODE == 2) ? ((rb >> 1) + ((rb & 1) << 12)) : rb;
        bptr[i] = B + (size_t)srow * ldb + c * 8;
    }

    auto stage = [&](int buf) {
#pragma unroll
        for (int i = 0; i < 4; ++i) {
            gload_lds16(aptr[i], &As[buf][(i * 512 + t) * 8]);
            aptr[i] += 64;
        }
#pragma unroll
        for (int i = 0; i < 2; ++i) {
            gload_lds16(bptr[i], &Bs[buf][(i * 512 + t) * 8]);
            bptr[i] += 64;
        }
    };

    // fragment LDS byte offsets (kt-invariant, hoisted)
    const int e = l31 & 7;
    int aoff[2][4], boff[2][4];
#pragma unroll
    for (int mi = 0; mi < 2; ++mi)
#pragma unroll
        for (int ks = 0; ks < 4; ++ks)
            aoff[mi][ks] = (wm + mi * 32 + l31) * 128 + (((ks * 2 + hi) ^ e) * 16);
#pragma unroll
    for (int ni = 0; ni < 2; ++ni)
#pragma unroll
        for (int ks = 0; ks < 4; ++ks)
            boff[ni][ks] = (wn + ni * 32 + l31) * 128 + (((ks * 2 + hi) ^ e) * 16);

    f32x16 acc[2][2] = {};

    const int NT = K >> 6;
    stage(0);
    stage(1);
    asm volatile("s_waitcnt vmcnt(6)\n\ts_barrier" ::: "memory");  // tile0 landed

    int buf = 0;
    for (int kt = 0; kt < NT; ++kt) {
        const char* abase = (const char*)&As[buf][0];
        const char* bbase = (const char*)&Bs[buf][0];
        bf16x8 af[2][4], bfr[2][4];
#pragma unroll
        for (int mi = 0; mi < 2; ++mi)
#pragma unroll
            for (int ks = 0; ks < 4; ++ks)
                af[mi][ks] = *reinterpret_cast<const bf16x8*>(abase + aoff[mi][ks]);
#pragma unroll
        for (int ni = 0; ni < 2; ++ni)
#pragma unroll
            for (int ks = 0; ks < 4; ++ks)
                bfr[ni][ks] = *reinterpret_cast<const bf16x8*>(bbase + boff[ni][ks]);
        int nbuf = buf + 2; if (nbuf >= 3) nbuf -= 3;
        if (kt + 2 < NT) stage(nbuf);
#pragma unroll
        for (int ks = 0; ks < 4; ++ks)
#pragma unroll
            for (int mi = 0; mi < 2; ++mi)
#pragma unroll
                for (int ni = 0; ni < 2; ++ni)
                    acc[mi][ni] = MFMA32(af[mi][ks], bfr[ni][ks], acc[mi][ni]);
        // counted wait: tile kt+1 landed, tile kt+2's 6 loads stay in flight
        if (kt + 2 < NT) {
            asm volatile("s_waitcnt vmcnt(6)\n\ts_barrier" ::: "memory");
        } else {
            asm volatile("s_waitcnt vmcnt(0)\n\ts_barrier" ::: "memory");
        }
        buf += 1; if (buf >= 3) buf = 0;
    }

    // epilogue: D col = l31, row = (r&3) + 8*(r>>2) + 4*hi
    const int row0 = bm * 256 + wm + 4 * hi;
    const int col0 = bn * 128 + wn + l31;
#pragma unroll
    for (int mi = 0; mi < 2; ++mi)
#pragma unroll
        for (int ni = 0; ni < 2; ++ni)
#pragma unroll
            for (int r = 0; r < 16; ++r) {
                int row = row0 + mi * 32 + (r & 3) + 8 * (r >> 2);
                int col = col0 + ni * 32;
                float v = acc[mi][ni][r];
                if (MODE == 0) {
                    outb[(size_t)row * ldo + col] = (__bf16)v;
                } else {
                    float pv = __shfl_xor(v, 1);   // partner column (col parity = l31&1)
                    if (!(l31 & 1)) {
                        float sg = v / (1.0f + __expf(-v));
                        outb[(size_t)row * ldo + (col >> 1)] = (__bf16)(sg * pv);
                    }
                }
            }
}

// ---------- NT GEMM (small-N path, unchanged R3 structure) ----------
// tile 128 x (NB*32), BK=64, 4 waves (2x2). MODE 1: out f32 = acc + resid.
template <int MODE, int NB>
__global__ __launch_bounds__(256) void gemm_nt(const __bf16* __restrict__ A, int lda,
                                               const __bf16* __restrict__ B, int ldb,
                                               __bf16* __restrict__ outb,
                                               float* __restrict__ outf,
                                               const float* __restrict__ resid,
                                               int K, int ldo) {
    constexpr int BN = NB * 32;
    __shared__ __attribute__((aligned(16))) __bf16 As[128 * 64];
    __shared__ __attribute__((aligned(16))) __bf16 Bs[BN * 64];
    const int t = threadIdx.x;
    const int lane = t & 63;
    const int wid = t >> 6;
    const int bm = blockIdx.x, bn = blockIdx.y;
    const int wm = (wid >> 1) * 64, wn = (wid & 1) * (NB * 16);
    f32x4 acc[4][NB] = {};

    for (int kt = 0; kt < K; kt += 64) {
        __syncthreads();
#pragma unroll
        for (int i = 0; i < 4; ++i) {
            int L = i * 256 + t;
            int r = L >> 3, s = L & 7;
            int c = s ^ (r & 7);
            gload_lds16(A + (size_t)(bm * 128 + r) * lda + kt + c * 8, As + L * 8);
        }
#pragma unroll
        for (int i = 0; i < NB; ++i) {
            int L = i * 256 + t;
            int r = L >> 3, s = L & 7;
            int c = s ^ (r & 7);
            int rb = bn * BN + r;
            gload_lds16(B + (size_t)rb * ldb + kt + c * 8, Bs + L * 8);
        }
        __syncthreads();
#pragma unroll
        for (int ks = 0; ks < 2; ++ks) {
            bf16x8 af[4], bfr[NB];
#pragma unroll
            for (int mi = 0; mi < 4; ++mi) {
                int r = wm + mi * 16 + (lane & 15);
                int slot = (ks * 4 + (lane >> 4)) ^ (r & 7);
                af[mi] = *reinterpret_cast<const bf16x8*>(As + r * 64 + slot * 8);
            }
#pragma unroll
            for (int ni = 0; ni < NB; ++ni) {
                int r = wn + ni * 16 + (lane & 15);
                int slot = (ks * 4 + (lane >> 4)) ^ (r & 7);
                bfr[ni] = *reinterpret_cast<const bf16x8*>(Bs + r * 64 + slot * 8);
            }
#pragma unroll
            for (int mi = 0; mi < 4; ++mi)
#pragma unroll
                for (int ni = 0; ni < NB; ++ni)
                    acc[mi][ni] = MFMA_BF16(af[mi], bfr[ni], acc[mi][ni]);
        }
    }
    const int row0 = bm * 128 + wm + ((lane >> 4) << 2);
    const int col0 = bn * BN + wn + (lane & 15);
#pragma unroll
    for (int mi = 0; mi < 4; ++mi)
#pragma unroll
        for (int ni = 0; ni < NB; ++ni)
#pragma unroll
            for (int r2 = 0; r2 < 4; ++r2) {
                int row = row0 + mi * 16 + r2;
                int col = col0 + ni * 16;
                float v = acc[mi][ni][r2];
                if (MODE == 0) {
                    outb[(size_t)row * ldo + col] = (__bf16)v;
                } else {
                    size_t idx = (size_t)row * ldo + col;
                    outf[idx] = v + resid[idx];
                }
            }
}

// ---------- V transpose: qkv V block [n][hd] -> vt [bh][hd][n] ----------
__global__ __launch_bounds__(256) void vtrans_kernel(const __bf16* __restrict__ qkv,
                                                     __bf16* __restrict__ vt) {
    __shared__ __bf16 T[64][68];
    const int t = threadIdx.x;
    const int bh = blockIdx.y, b = bh >> 4, h = bh & 15;
    const int n0 = blockIdx.x * 64;
    const __bf16* vp = qkv + (size_t)b * 2048 * 3072 + 2048 + h * 64;
#pragma unroll
    for (int i = 0; i < 2; ++i) {
        int r = i * 32 + (t >> 3), c = t & 7;
        bf16x8 v = *reinterpret_cast<const bf16x8*>(vp + (size_t)(n0 + r) * 3072 + c * 8);
#pragma unroll
        for (int j = 0; j < 8; ++j) T[c * 8 + j][r] = v[j];
    }
    __syncthreads();
#pragma unroll
    for (int i = 0; i < 2; ++i) {
        int hd = i * 32 + (t >> 3), c = t & 7;
        bf16x8 v;
#pragma unroll
        for (int j = 0; j < 8; ++j) v[j] = T[hd][c * 8 + j];
        *reinterpret_cast<bf16x8*>(vt + ((size_t)bh * 64 + hd) * 2048 + n0 + c * 8) = v;
    }
}

// ---------- flash attention v3 (unchanged) ----------
__global__ __launch_bounds__(256) void attn_kernel(const __bf16* __restrict__ qkv,
                                                   const __bf16* __restrict__ vt,
                                                   __bf16* __restrict__ o) {
    __shared__ __attribute__((aligned(16))) __bf16 Ks[2][128 * 64];
    __shared__ __attribute__((aligned(16))) __bf16 Vs[2][64 * 128];
    const int t = threadIdx.x;
    const int lane = t & 63;
    const int w = t >> 6;
    const int hi = lane >> 5;
    const int l31 = lane & 31;
    const int bh = blockIdx.y;
    const int b = bh >> 4, h = bh & 15;
    const __bf16* qp = qkv + (size_t)b * 2048 * 3072 + h * 64;
    const __bf16* kp = qp + 1024;
    const __bf16* vtp = vt + (size_t)bh * 64 * 2048;
    const int q0 = blockIdx.x * 128 + w * 32;

    const float SC = 0.18033688011112042f;
    bf16x8 qf[4];
#pragma unroll
    for (int s = 0; s < 4; ++s) {
        bf16x8 raw = *reinterpret_cast<const bf16x8*>(
            qp + (size_t)(q0 + l31) * 3072 + s * 16 + hi * 8);
        bf16x8 sc;
#pragma unroll
        for (int j = 0; j < 8; ++j) sc[j] = (__bf16)((float)raw[j] * SC);
        qf[s] = sc;
    }

    f32x16 oa[2] = {};
    float m_run = -INFINITY, l_run = 0.0f;

    auto stage = [&](int buf, int kt) {
#pragma unroll
        for (int i = 0; i < 4; ++i) {
            int L = i * 256 + t;
            int r = L >> 3, s = L & 7;
            int c = s ^ (r & 7);
            gload_lds16(kp + (size_t)(kt + r) * 3072 + c * 8, &Ks[buf][L * 8]);
        }
#pragma unroll
        for (int i = 0; i < 4; ++i) {
            int L = i * 256 + t;
            int r = L >> 4, s = L & 15;
            int c = s ^ (r & 15);
            gload_lds16(vtp + (size_t)r * 2048 + kt + c * 8, &Vs[buf][L * 8]);
        }
    };
    stage(0, 0);
    __syncthreads();

    for (int kt = 0; kt < 2048; kt += 128) {
        const int buf = (kt >> 7) & 1;
        if (kt + 128 < 2048) stage(buf ^ 1, kt + 128);

#pragma unroll
        for (int h2 = 0; h2 < 2; ++h2) {
            f32x16 st[2] = {};
#pragma unroll
            for (int s = 0; s < 4; ++s) {
#pragma unroll
                for (int mb = 0; mb < 2; ++mb) {
                    int r = h2 * 64 + mb * 32 + l31;
                    int sl = (s * 2 + hi) ^ (r & 7);
                    bf16x8 kf = *reinterpret_cast<const bf16x8*>(&Ks[buf][r * 64 + sl * 8]);
                    st[mb] = MFMA32(kf, qf[s], st[mb]);
                }
            }
            float mt = -INFINITY;
#pragma unroll
            for (int mb = 0; mb < 2; ++mb)
#pragma unroll
                for (int r = 0; r < 16; ++r) mt = fmaxf(mt, st[mb][r]);
            mt = fmaxf(mt, __shfl_xor(mt, 32));
            if (__any(mt > m_run + 8.0f)) {
                float m_new = fmaxf(m_run, mt);
                float alpha = exp2f(m_run - m_new);
#pragma unroll
                for (int r = 0; r < 16; ++r) {
                    float av = __shfl(alpha, (r & 3) + 8 * (r >> 2) + 4 * hi);
                    oa[0][r] *= av;
                    oa[1][r] *= av;
                }
                l_run *= alpha;
                m_run = m_new;
            }
            float ps = 0.0f;
#pragma unroll
            for (int mb = 0; mb < 2; ++mb)
#pragma unroll
                for (int r = 0; r < 16; ++r) {
                    float p = exp2f(st[mb][r] - m_run);
                    st[mb][r] = p;
                    ps += p;
                }
            ps += __shfl_xor(ps, 32);
            l_run += ps;

            uint32_t pk[16];
#pragma unroll
            for (int mb = 0; mb < 2; ++mb)
#pragma unroll
                for (int i2 = 0; i2 < 8; ++i2)
                    pk[mb * 8 + i2] = pack2(st[mb][2 * i2], st[mb][2 * i2 + 1]);

#pragma unroll
            for (int s2 = 0; s2 < 4; ++s2) {
                const int I0 = (s2 >> 1) * 8 + (s2 & 1) * 4;
                u32x2 w02 = __builtin_amdgcn_permlane32_swap(pk[I0], pk[I0 + 2], false, false);
                u32x2 w13 = __builtin_amdgcn_permlane32_swap(pk[I0 + 1], pk[I0 + 3], false, false);
                u32x4 fv;
                fv[0] = w02[0]; fv[1] = w13[0]; fv[2] = w02[1]; fv[3] = w13[1];
                bf16x8 pa = __builtin_bit_cast(bf16x8, fv);
#pragma unroll
                for (int nb = 0; nb < 2; ++nb) {
                    int rv = nb * 32 + l31;
                    int ch = h2 * 8 + s2 * 2 + hi;
                    int sl = ch ^ (rv & 15);
                    bf16x8 vf = *reinterpret_cast<const bf16x8*>(&Vs[buf][rv * 128 + sl * 8]);
                    oa[nb] = MFMA32(pa, vf, oa[nb]);
                }
            }
        }
        __syncthreads();
    }

#pragma unroll
    for (int r = 0; r < 16; ++r) {
        int crow = (r & 3) + 8 * (r >> 2) + 4 * hi;
        float lv = __shfl(l_run, crow);
        float inv = 1.0f / lv;
        int row = q0 + crow;
        size_t base = ((size_t)b * 2048 + row) * 1024 + h * 64 + l31;
        o[base]      = (__bf16)(oa[0][r] * inv);
        o[base + 32] = (__bf16)(oa[1][r] * inv);
    }
}

// ---------- launch ----------
extern "C" void kernel_launch(void* const* d_in, const int* in_sizes, int n_in,
                              void* d_out, int out_size, void* d_ws, size_t ws_size,
                              hipStream_t stream) {
    const float* x      = (const float*)d_in[0];
    const float* w_qkv  = (const float*)d_in[3];
    const float* w_o    = (const float*)d_in[4];
    const float* w1     = (const float*)d_in[5];
    const float* w2     = (const float*)d_in[6];
    const float* g_attn = (const float*)d_in[7];
    const float* g_ff   = (const float*)d_in[8];
    float* out = (float*)d_out;

    char* ws = (char*)d_ws;
    size_t off = 0;
    auto alloc = [&](size_t bytes) -> void* {
        void* p = ws + off;
        off += (bytes + 255) & ~(size_t)255;
        return p;
    };
    __bf16* wqkv_b = (__bf16*)alloc((size_t)3072 * 1024 * 2);
    __bf16* wo_b   = (__bf16*)alloc((size_t)1024 * 1024 * 2);
    __bf16* w1_b   = (__bf16*)alloc((size_t)8192 * 1024 * 2);
    __bf16* w2_b   = (__bf16*)alloc((size_t)1024 * 4096 * 2);
    __bf16* h_b    = (__bf16*)alloc((size_t)4096 * 1024 * 2);
    __bf16* qkv_b  = (__bf16*)alloc((size_t)4096 * 3072 * 2);
    __bf16* o_b    = (__bf16*)alloc((size_t)4096 * 1024 * 2);
    float*  x2     = (float*)alloc((size_t)4096 * 1024 * 4);
    __bf16* vt_b   = (__bf16*)alloc((size_t)32 * 64 * 2048 * 2);
    __bf16* act_b  = qkv_b;  // alias: act over [qkv|o] (dead after o-proj)

    cvt_kernel<<<3072, 256, 0, stream>>>(w_qkv, wqkv_b);
    cvt_kernel<<<1024, 256, 0, stream>>>(w_o, wo_b);
    cvt_kernel<<<8192, 256, 0, stream>>>(w1, w1_b);
    cvt_kernel<<<4096, 256, 0, stream>>>(w2, w2_b);

    rmsnorm_kernel<<<4096, 256, 0, stream>>>(x, g_attn, h_b);
    // qkv: pipelined path, 256x128 tiles
    gemm_pipe<0><<<dim3(16, 24), 512, 0, stream>>>(h_b, 1024, wqkv_b, 1024,
                                                   qkv_b, 1024, 3072);
    vtrans_kernel<<<dim3(32, 32), 256, 0, stream>>>(qkv_b, vt_b);
    attn_kernel<<<dim3(16, 32), 256, 0, stream>>>(qkv_b, vt_b, o_b);
    gemm_nt<1, 2><<<dim3(32, 16), 256, 0, stream>>>(o_b, 1024, wo_b, 1024,
                                                    nullptr, x2, x, 1024, 1024);
    rmsnorm_kernel<<<4096, 256, 0, stream>>>(x2, g_ff, h_b);
    // ffn1: pipelined path + fused SwiGLU
    gemm_pipe<2><<<dim3(16, 64), 512, 0, stream>>>(h_b, 1024, w1_b, 1024,
                                                   act_b, 1024, 4096);
    gemm_nt<1, 2><<<dim3(32, 16), 256, 0, stream>>>(act_b, 4096, w2_b, 4096,
                                                    nullptr, out, x2, 4096, 1024);
}

// Round 5
// 321.260 us; speedup vs baseline: 1.0497x; 1.0497x over previous
//
#include <hip/hip_runtime.h>
#include <cstdint>
#include <cstddef>

// ---------- types ----------
typedef __attribute__((ext_vector_type(8)))  __bf16 bf16x8;
typedef __attribute__((ext_vector_type(4)))  __bf16 bf16x4;
typedef __attribute__((ext_vector_type(4)))  float  f32x4;
typedef __attribute__((ext_vector_type(16))) float  f32x16;
typedef __attribute__((ext_vector_type(2)))  uint32_t u32x2;
typedef __attribute__((ext_vector_type(4)))  uint32_t u32x4;

#define MFMA_BF16(a, b, c) __builtin_amdgcn_mfma_f32_16x16x32_bf16((a), (b), (c), 0, 0, 0)
#define MFMA32(a, b, c)    __builtin_amdgcn_mfma_f32_32x32x16_bf16((a), (b), (c), 0, 0, 0)

// async global->LDS, 16B per lane. LDS dest must be wave-uniform base + lane*16.
__device__ __forceinline__ void gload_lds16(const __bf16* src, __bf16* lds_dst) {
    __builtin_amdgcn_global_load_lds(
        (const __attribute__((address_space(1))) void*)(const_cast<__bf16*>(src)),
        (__attribute__((address_space(3))) void*)(lds_dst), 16, 0, 0);
}

__device__ __forceinline__ uint32_t pack2(float a, float b) {
    uint16_t ua = __builtin_bit_cast(uint16_t, (__bf16)a);
    uint16_t ub = __builtin_bit_cast(uint16_t, (__bf16)b);
    return (uint32_t)ua | ((uint32_t)ub << 16);
}

__device__ __forceinline__ bf16x8 ldv(const void* p) {
    return *reinterpret_cast<const bf16x8*>(p);
}

// ---------- fp32 -> bf16 convert ----------
__global__ __launch_bounds__(256) void cvt_kernel(const float* __restrict__ src,
                                                  __bf16* __restrict__ dst) {
    int i = blockIdx.x * 256 + threadIdx.x;
    float4 v = reinterpret_cast<const float4*>(src)[i];
    bf16x4 o;
    o[0] = (__bf16)v.x; o[1] = (__bf16)v.y; o[2] = (__bf16)v.z; o[3] = (__bf16)v.w;
    reinterpret_cast<bf16x4*>(dst)[i] = o;
}

// ---------- RMSNorm (row = 1024 fp32) -> bf16 ----------
__global__ __launch_bounds__(256) void rmsnorm_kernel(const float* __restrict__ x,
                                                      const float* __restrict__ g,
                                                      __bf16* __restrict__ out) {
    const int row = blockIdx.x;
    const int t = threadIdx.x;
    float4 v = reinterpret_cast<const float4*>(x + (size_t)row * 1024)[t];
    float ss = v.x * v.x + v.y * v.y + v.z * v.z + v.w * v.w;
#pragma unroll
    for (int m = 1; m < 64; m <<= 1) ss += __shfl_xor(ss, m);
    __shared__ float sred[4];
    if ((t & 63) == 0) sred[t >> 6] = ss;
    __syncthreads();
    float tot = sred[0] + sred[1] + sred[2] + sred[3];
    float rs = rsqrtf(tot * (1.0f / 1024.0f) + 1.1920928955078125e-07f);
    float4 gv = reinterpret_cast<const float4*>(g)[t];
    bf16x4 o;
    o[0] = (__bf16)(v.x * rs * gv.x);
    o[1] = (__bf16)(v.y * rs * gv.y);
    o[2] = (__bf16)(v.z * rs * gv.z);
    o[3] = (__bf16)(v.w * rs * gv.w);
    *reinterpret_cast<bf16x4*>(out + (size_t)row * 1024 + t * 4) = o;
}

// ---------- 8-phase NT GEMM (m201 template): C[m,n] = sum_k A[m,k]*B[n,k] ----------
// BM=BN=256, BK=64; 512 thr = 8 waves (2Mx4N); per-wave 128x64; 16x16x32 MFMA.
// LDS: 8 half-tile slots x 16KB (per K-tile: A-klo, B-klo, A-khi, B-khi; 2 K-tiles).
// 4 phases/K-tile: {ds_read 8|4, stage 1 half-tile, barrier, setprio+16 MFMA, barrier}.
// vmcnt(4) once per K-tile. Staging 6 half-tiles ahead; overwrite-issue is barrier-
// ordered >= 1 phase after the slot's last read (race-free by ordering).
// MODE 0: out bf16. MODE 2: FFN1+SwiGLU fused (B rows permuted; pair via shfl_xor(1)).
template <int MODE>
__global__ __launch_bounds__(512, 2) void gemm_8p(const __bf16* __restrict__ A, int lda,
                                                  const __bf16* __restrict__ B, int ldb,
                                                  __bf16* __restrict__ outb,
                                                  int K, int ldo) {
    __shared__ __attribute__((aligned(16))) __bf16 Sl[8][256 * 32];
    const int t = threadIdx.x;
    const int lane = t & 63;
    const int wid = t >> 6;
    const int l15 = lane & 15;
    const int g4 = lane >> 4;           // k-chunk 0..3 within 32-slice
    const int bm = blockIdx.x, bn = blockIdx.y;
    const int wm = (wid >> 2) * 128;    // 0,128
    const int wn = (wid & 3) * 64;      // 0,64,128,192

    // staging source pointers (2 x 16B chunks per thread per half-tile), +32 elems/stage
    const __bf16 *pa[2], *pb[2];
#pragma unroll
    for (int i = 0; i < 2; ++i) {
        int L = i * 512 + t, r = L >> 2, c = (L & 3) ^ ((r >> 1) & 3);
        pa[i] = A + (size_t)(bm * 256 + r) * lda + c * 8;
        int rb = bn * 256 + r;
        int srow = (MODE == 2) ? ((rb >> 1) + ((rb & 1) << 12)) : rb;
        pb[i] = B + (size_t)srow * ldb + c * 8;
    }
    auto stageA = [&](int slot) {
#pragma unroll
        for (int i = 0; i < 2; ++i) {
            gload_lds16(pa[i], &Sl[slot][(i * 512 + t) * 8]);
            pa[i] += 32;
        }
    };
    auto stageB = [&](int slot) {
#pragma unroll
        for (int i = 0; i < 2; ++i) {
            gload_lds16(pb[i], &Sl[slot][(i * 512 + t) * 8]);
            pb[i] += 32;
        }
    };

    // fragment byte offsets within a slot (row = 64B; chunk XOR-swizzled)
    int aoff[8], boff[4];
#pragma unroll
    for (int m = 0; m < 8; ++m) {
        int r = wm + m * 16 + l15;
        aoff[m] = r * 64 + ((g4 ^ ((r >> 1) & 3)) * 16);
    }
#pragma unroll
    for (int n = 0; n < 4; ++n) {
        int r = wn + n * 16 + l15;
        boff[n] = r * 64 + ((g4 ^ ((r >> 1) & 3)) * 16);
    }

    f32x4 acc[8][4] = {};
    const int NT = K >> 6;

    // prologue: 6 half-tiles (tile0 complete + tile1 klo halves)
    stageA(0); stageB(1); stageA(2); stageB(3); stageA(4); stageB(5);
    asm volatile("s_waitcnt vmcnt(4)" ::: "memory");
    __builtin_amdgcn_s_barrier();

    for (int tt = 0; tt < NT; ++tt) {
        const int q = (tt & 1) * 4, nq = q ^ 4;
        const char* Alo = (const char*)&Sl[q + 0][0];
        const char* Blo = (const char*)&Sl[q + 1][0];
        const char* Ahi = (const char*)&Sl[q + 2][0];
        const char* Bhi = (const char*)&Sl[q + 3][0];
        bf16x8 af[4], bf[4];

        // ---- phase 0: klo, mfrag 0-3 (reads A-klo + B-klo); stage A-khi(t+1)
#pragma unroll
        for (int m = 0; m < 4; ++m) af[m] = ldv(Alo + aoff[m]);
#pragma unroll
        for (int n = 0; n < 4; ++n) bf[n] = ldv(Blo + boff[n]);
        if (tt + 1 < NT) stageA(nq + 2);
        __builtin_amdgcn_s_barrier();
        __builtin_amdgcn_s_setprio(1);
#pragma unroll
        for (int m = 0; m < 4; ++m)
#pragma unroll
            for (int n = 0; n < 4; ++n)
                acc[m][n] = MFMA_BF16(af[m], bf[n], acc[m][n]);
        __builtin_amdgcn_s_setprio(0);
        __builtin_amdgcn_s_barrier();

        // ---- phase 1: klo, mfrag 4-7 (B regs reused); stage B-khi(t+1)
#pragma unroll
        for (int m = 0; m < 4; ++m) af[m] = ldv(Alo + aoff[4 + m]);
        if (tt + 1 < NT) stageB(nq + 3);
        __builtin_amdgcn_s_barrier();
        __builtin_amdgcn_s_setprio(1);
#pragma unroll
        for (int m = 0; m < 4; ++m)
#pragma unroll
            for (int n = 0; n < 4; ++n)
                acc[4 + m][n] = MFMA_BF16(af[m], bf[n], acc[4 + m][n]);
        __builtin_amdgcn_s_setprio(0);
        __builtin_amdgcn_s_barrier();

        // ---- phase 2: khi, mfrag 0-3 (reads A-khi + B-khi); stage A-klo(t+2)
#pragma unroll
        for (int m = 0; m < 4; ++m) af[m] = ldv(Ahi + aoff[m]);
#pragma unroll
        for (int n = 0; n < 4; ++n) bf[n] = ldv(Bhi + boff[n]);
        if (tt + 2 < NT) stageA(q + 0);
        __builtin_amdgcn_s_barrier();
        __builtin_amdgcn_s_setprio(1);
#pragma unroll
        for (int m = 0; m < 4; ++m)
#pragma unroll
            for (int n = 0; n < 4; ++n)
                acc[m][n] = MFMA_BF16(af[m], bf[n], acc[m][n]);
        __builtin_amdgcn_s_setprio(0);
        __builtin_amdgcn_s_barrier();

        // ---- phase 3: khi, mfrag 4-7; stage B-klo(t+2); K-tile boundary vmcnt
#pragma unroll
        for (int m = 0; m < 4; ++m) af[m] = ldv(Ahi + aoff[4 + m]);
        if (tt + 2 < NT) stageB(q + 1);
        __builtin_amdgcn_s_barrier();
        __builtin_amdgcn_s_setprio(1);
#pragma unroll
        for (int m = 0; m < 4; ++m)
#pragma unroll
            for (int n = 0; n < 4; ++n)
                acc[4 + m][n] = MFMA_BF16(af[m], bf[n], acc[4 + m][n]);
        __builtin_amdgcn_s_setprio(0);
        if (tt + 2 < NT) {
            asm volatile("s_waitcnt vmcnt(4)" ::: "memory");
        } else {
            asm volatile("s_waitcnt vmcnt(0)" ::: "memory");
        }
        __builtin_amdgcn_s_barrier();
    }

    // epilogue: C/D layout col = lane&15, row = (lane>>4)*4 + reg
    const int row0 = bm * 256 + wm + (g4 << 2);
    const int col0 = bn * 256 + wn + l15;
#pragma unroll
    for (int m = 0; m < 8; ++m)
#pragma unroll
        for (int n = 0; n < 4; ++n)
#pragma unroll
            for (int r2 = 0; r2 < 4; ++r2) {
                int row = row0 + m * 16 + r2;
                int col = col0 + n * 16;
                float v = acc[m][n][r2];
                if (MODE == 0) {
                    outb[(size_t)row * ldo + col] = (__bf16)v;
                } else {
                    float pv = __shfl_xor(v, 1);
                    if (!(l15 & 1)) {
                        float sg = v / (1.0f + __expf(-v));
                        outb[(size_t)row * ldo + (col >> 1)] = (__bf16)(sg * pv);
                    }
                }
            }
}

// ---------- NT GEMM (small-N path, R3 structure) ----------
// tile 128 x (NB*32), BK=64, 4 waves (2x2). MODE 1: out f32 = acc + resid.
template <int MODE, int NB>
__global__ __launch_bounds__(256) void gemm_nt(const __bf16* __restrict__ A, int lda,
                                               const __bf16* __restrict__ B, int ldb,
                                               __bf16* __restrict__ outb,
                                               float* __restrict__ outf,
                                               const float* __restrict__ resid,
                                               int K, int ldo) {
    constexpr int BN = NB * 32;
    __shared__ __attribute__((aligned(16))) __bf16 As[128 * 64];
    __shared__ __attribute__((aligned(16))) __bf16 Bs[BN * 64];
    const int t = threadIdx.x;
    const int lane = t & 63;
    const int wid = t >> 6;
    const int bm = blockIdx.x, bn = blockIdx.y;
    const int wm = (wid >> 1) * 64, wn = (wid & 1) * (NB * 16);
    f32x4 acc[4][NB] = {};

    for (int kt = 0; kt < K; kt += 64) {
        __syncthreads();
#pragma unroll
        for (int i = 0; i < 4; ++i) {
            int L = i * 256 + t;
            int r = L >> 3, s = L & 7;
            int c = s ^ (r & 7);
            gload_lds16(A + (size_t)(bm * 128 + r) * lda + kt + c * 8, As + L * 8);
        }
#pragma unroll
        for (int i = 0; i < NB; ++i) {
            int L = i * 256 + t;
            int r = L >> 3, s = L & 7;
            int c = s ^ (r & 7);
            int rb = bn * BN + r;
            gload_lds16(B + (size_t)rb * ldb + kt + c * 8, Bs + L * 8);
        }
        __syncthreads();
#pragma unroll
        for (int ks = 0; ks < 2; ++ks) {
            bf16x8 af[4], bfr[NB];
#pragma unroll
            for (int mi = 0; mi < 4; ++mi) {
                int r = wm + mi * 16 + (lane & 15);
                int slot = (ks * 4 + (lane >> 4)) ^ (r & 7);
                af[mi] = *reinterpret_cast<const bf16x8*>(As + r * 64 + slot * 8);
            }
#pragma unroll
            for (int ni = 0; ni < NB; ++ni) {
                int r = wn + ni * 16 + (lane & 15);
                int slot = (ks * 4 + (lane >> 4)) ^ (r & 7);
                bfr[ni] = *reinterpret_cast<const bf16x8*>(Bs + r * 64 + slot * 8);
            }
#pragma unroll
            for (int mi = 0; mi < 4; ++mi)
#pragma unroll
                for (int ni = 0; ni < NB; ++ni)
                    acc[mi][ni] = MFMA_BF16(af[mi], bfr[ni], acc[mi][ni]);
        }
    }
    const int row0 = bm * 128 + wm + ((lane >> 4) << 2);
    const int col0 = bn * BN + wn + (lane & 15);
#pragma unroll
    for (int mi = 0; mi < 4; ++mi)
#pragma unroll
        for (int ni = 0; ni < NB; ++ni)
#pragma unroll
            for (int r2 = 0; r2 < 4; ++r2) {
                int row = row0 + mi * 16 + r2;
                int col = col0 + ni * 16;
                float v = acc[mi][ni][r2];
                if (MODE == 0) {
                    outb[(size_t)row * ldo + col] = (__bf16)v;
                } else {
                    size_t idx = (size_t)row * ldo + col;
                    outf[idx] = v + resid[idx];
                }
            }
}

// ---------- V transpose: qkv V block [n][hd] -> vt [bh][hd][n] ----------
__global__ __launch_bounds__(256) void vtrans_kernel(const __bf16* __restrict__ qkv,
                                                     __bf16* __restrict__ vt) {
    __shared__ __bf16 T[64][68];
    const int t = threadIdx.x;
    const int bh = blockIdx.y, b = bh >> 4, h = bh & 15;
    const int n0 = blockIdx.x * 64;
    const __bf16* vp = qkv + (size_t)b * 2048 * 3072 + 2048 + h * 64;
#pragma unroll
    for (int i = 0; i < 2; ++i) {
        int r = i * 32 + (t >> 3), c = t & 7;
        bf16x8 v = *reinterpret_cast<const bf16x8*>(vp + (size_t)(n0 + r) * 3072 + c * 8);
#pragma unroll
        for (int j = 0; j < 8; ++j) T[c * 8 + j][r] = v[j];
    }
    __syncthreads();
#pragma unroll
    for (int i = 0; i < 2; ++i) {
        int hd = i * 32 + (t >> 3), c = t & 7;
        bf16x8 v;
#pragma unroll
        for (int j = 0; j < 8; ++j) v[j] = T[hd][c * 8 + j];
        *reinterpret_cast<bf16x8*>(vt + ((size_t)bh * 64 + hd) * 2048 + n0 + c * 8) = v;
    }
}

// ---------- flash attention v3 (R3, unchanged) ----------
__global__ __launch_bounds__(256) void attn_kernel(const __bf16* __restrict__ qkv,
                                                   const __bf16* __restrict__ vt,
                                                   __bf16* __restrict__ o) {
    __shared__ __attribute__((aligned(16))) __bf16 Ks[2][128 * 64];
    __shared__ __attribute__((aligned(16))) __bf16 Vs[2][64 * 128];
    const int t = threadIdx.x;
    const int lane = t & 63;
    const int w = t >> 6;
    const int hi = lane >> 5;
    const int l31 = lane & 31;
    const int bh = blockIdx.y;
    const int b = bh >> 4, h = bh & 15;
    const __bf16* qp = qkv + (size_t)b * 2048 * 3072 + h * 64;
    const __bf16* kp = qp + 1024;
    const __bf16* vtp = vt + (size_t)bh * 64 * 2048;
    const int q0 = blockIdx.x * 128 + w * 32;

    const float SC = 0.18033688011112042f;
    bf16x8 qf[4];
#pragma unroll
    for (int s = 0; s < 4; ++s) {
        bf16x8 raw = *reinterpret_cast<const bf16x8*>(
            qp + (size_t)(q0 + l31) * 3072 + s * 16 + hi * 8);
        bf16x8 sc;
#pragma unroll
        for (int j = 0; j < 8; ++j) sc[j] = (__bf16)((float)raw[j] * SC);
        qf[s] = sc;
    }

    f32x16 oa[2] = {};
    float m_run = -INFINITY, l_run = 0.0f;

    auto stage = [&](int buf, int kt) {
#pragma unroll
        for (int i = 0; i < 4; ++i) {
            int L = i * 256 + t;
            int r = L >> 3, s = L & 7;
            int c = s ^ (r & 7);
            gload_lds16(kp + (size_t)(kt + r) * 3072 + c * 8, &Ks[buf][L * 8]);
        }
#pragma unroll
        for (int i = 0; i < 4; ++i) {
            int L = i * 256 + t;
            int r = L >> 4, s = L & 15;
            int c = s ^ (r & 15);
            gload_lds16(vtp + (size_t)r * 2048 + kt + c * 8, &Vs[buf][L * 8]);
        }
    };
    stage(0, 0);
    __syncthreads();

    for (int kt = 0; kt < 2048; kt += 128) {
        const int buf = (kt >> 7) & 1;
        if (kt + 128 < 2048) stage(buf ^ 1, kt + 128);

#pragma unroll
        for (int h2 = 0; h2 < 2; ++h2) {
            f32x16 st[2] = {};
#pragma unroll
            for (int s = 0; s < 4; ++s) {
#pragma unroll
                for (int mb = 0; mb < 2; ++mb) {
                    int r = h2 * 64 + mb * 32 + l31;
                    int sl = (s * 2 + hi) ^ (r & 7);
                    bf16x8 kf = *reinterpret_cast<const bf16x8*>(&Ks[buf][r * 64 + sl * 8]);
                    st[mb] = MFMA32(kf, qf[s], st[mb]);
                }
            }
            float mt = -INFINITY;
#pragma unroll
            for (int mb = 0; mb < 2; ++mb)
#pragma unroll
                for (int r = 0; r < 16; ++r) mt = fmaxf(mt, st[mb][r]);
            mt = fmaxf(mt, __shfl_xor(mt, 32));
            if (__any(mt > m_run + 8.0f)) {
                float m_new = fmaxf(m_run, mt);
                float alpha = exp2f(m_run - m_new);
#pragma unroll
                for (int r = 0; r < 16; ++r) {
                    float av = __shfl(alpha, (r & 3) + 8 * (r >> 2) + 4 * hi);
                    oa[0][r] *= av;
                    oa[1][r] *= av;
                }
                l_run *= alpha;
                m_run = m_new;
            }
            float ps = 0.0f;
#pragma unroll
            for (int mb = 0; mb < 2; ++mb)
#pragma unroll
                for (int r = 0; r < 16; ++r) {
                    float p = exp2f(st[mb][r] - m_run);
                    st[mb][r] = p;
                    ps += p;
                }
            ps += __shfl_xor(ps, 32);
            l_run += ps;

            uint32_t pk[16];
#pragma unroll
            for (int mb = 0; mb < 2; ++mb)
#pragma unroll
                for (int i2 = 0; i2 < 8; ++i2)
                    pk[mb * 8 + i2] = pack2(st[mb][2 * i2], st[mb][2 * i2 + 1]);

#pragma unroll
            for (int s2 = 0; s2 < 4; ++s2) {
                const int I0 = (s2 >> 1) * 8 + (s2 & 1) * 4;
                u32x2 w02 = __builtin_amdgcn_permlane32_swap(pk[I0], pk[I0 + 2], false, false);
                u32x2 w13 = __builtin_amdgcn_permlane32_swap(pk[I0 + 1], pk[I0 + 3], false, false);
                u32x4 fv;
                fv[0] = w02[0]; fv[1] = w13[0]; fv[2] = w02[1]; fv[3] = w13[1];
                bf16x8 pa = __builtin_bit_cast(bf16x8, fv);
#pragma unroll
                for (int nb = 0; nb < 2; ++nb) {
                    int rv = nb * 32 + l31;
                    int ch = h2 * 8 + s2 * 2 + hi;
                    int sl = ch ^ (rv & 15);
                    bf16x8 vf = *reinterpret_cast<const bf16x8*>(&Vs[buf][rv * 128 + sl * 8]);
                    oa[nb] = MFMA32(pa, vf, oa[nb]);
                }
            }
        }
        __syncthreads();
    }

#pragma unroll
    for (int r = 0; r < 16; ++r) {
        int crow = (r & 3) + 8 * (r >> 2) + 4 * hi;
        float lv = __shfl(l_run, crow);
        float inv = 1.0f / lv;
        int row = q0 + crow;
        size_t base = ((size_t)b * 2048 + row) * 1024 + h * 64 + l31;
        o[base]      = (__bf16)(oa[0][r] * inv);
        o[base + 32] = (__bf16)(oa[1][r] * inv);
    }
}

// ---------- launch ----------
extern "C" void kernel_launch(void* const* d_in, const int* in_sizes, int n_in,
                              void* d_out, int out_size, void* d_ws, size_t ws_size,
                              hipStream_t stream) {
    const float* x      = (const float*)d_in[0];
    const float* w_qkv  = (const float*)d_in[3];
    const float* w_o    = (const float*)d_in[4];
    const float* w1     = (const float*)d_in[5];
    const float* w2     = (const float*)d_in[6];
    const float* g_attn = (const float*)d_in[7];
    const float* g_ff   = (const float*)d_in[8];
    float* out = (float*)d_out;

    char* ws = (char*)d_ws;
    size_t off = 0;
    auto alloc = [&](size_t bytes) -> void* {
        void* p = ws + off;
        off += (bytes + 255) & ~(size_t)255;
        return p;
    };
    __bf16* wqkv_b = (__bf16*)alloc((size_t)3072 * 1024 * 2);
    __bf16* wo_b   = (__bf16*)alloc((size_t)1024 * 1024 * 2);
    __bf16* w1_b   = (__bf16*)alloc((size_t)8192 * 1024 * 2);
    __bf16* w2_b   = (__bf16*)alloc((size_t)1024 * 4096 * 2);
    __bf16* h_b    = (__bf16*)alloc((size_t)4096 * 1024 * 2);
    __bf16* qkv_b  = (__bf16*)alloc((size_t)4096 * 3072 * 2);
    __bf16* o_b    = (__bf16*)alloc((size_t)4096 * 1024 * 2);
    float*  x2     = (float*)alloc((size_t)4096 * 1024 * 4);
    __bf16* vt_b   = (__bf16*)alloc((size_t)32 * 64 * 2048 * 2);
    __bf16* act_b  = qkv_b;  // alias: act over [qkv|o] (dead after o-proj)

    cvt_kernel<<<3072, 256, 0, stream>>>(w_qkv, wqkv_b);
    cvt_kernel<<<1024, 256, 0, stream>>>(w_o, wo_b);
    cvt_kernel<<<8192, 256, 0, stream>>>(w1, w1_b);
    cvt_kernel<<<4096, 256, 0, stream>>>(w2, w2_b);

    rmsnorm_kernel<<<4096, 256, 0, stream>>>(x, g_attn, h_b);
    // qkv: 8-phase 256x256 tiles
    gemm_8p<0><<<dim3(16, 12), 512, 0, stream>>>(h_b, 1024, wqkv_b, 1024,
                                                 qkv_b, 1024, 3072);
    vtrans_kernel<<<dim3(32, 32), 256, 0, stream>>>(qkv_b, vt_b);
    attn_kernel<<<dim3(16, 32), 256, 0, stream>>>(qkv_b, vt_b, o_b);
    gemm_nt<1, 2><<<dim3(32, 16), 256, 0, stream>>>(o_b, 1024, wo_b, 1024,
                                                    nullptr, x2, x, 1024, 1024);
    rmsnorm_kernel<<<4096, 256, 0, stream>>>(x2, g_ff, h_b);
    // ffn1: 8-phase + fused SwiGLU
    gemm_8p<2><<<dim3(16, 32), 512, 0, stream>>>(h_b, 1024, w1_b, 1024,
                                                 act_b, 1024, 4096);
    gemm_nt<1, 2><<<dim3(32, 16), 256, 0, stream>>>(act_b, 4096, w2_b, 4096,
                                                    nullptr, out, x2, 4096, 1024);
}

// Round 6
// 313.682 us; speedup vs baseline: 1.0750x; 1.0242x over previous
//
#include <hip/hip_runtime.h>
#include <cstdint>
#include <cstddef>

// ---------- types ----------
typedef __attribute__((ext_vector_type(8)))  __bf16 bf16x8;
typedef __attribute__((ext_vector_type(4)))  __bf16 bf16x4;
typedef __attribute__((ext_vector_type(4)))  float  f32x4;
typedef __attribute__((ext_vector_type(16))) float  f32x16;
typedef __attribute__((ext_vector_type(2)))  uint32_t u32x2;
typedef __attribute__((ext_vector_type(4)))  uint32_t u32x4;

#define MFMA_BF16(a, b, c) __builtin_amdgcn_mfma_f32_16x16x32_bf16((a), (b), (c), 0, 0, 0)
#define MFMA32(a, b, c)    __builtin_amdgcn_mfma_f32_32x32x16_bf16((a), (b), (c), 0, 0, 0)

// async global->LDS, 16B per lane. LDS dest must be wave-uniform base + lane*16.
__device__ __forceinline__ void gload_lds16(const __bf16* src, __bf16* lds_dst) {
    __builtin_amdgcn_global_load_lds(
        (const __attribute__((address_space(1))) void*)(const_cast<__bf16*>(src)),
        (__attribute__((address_space(3))) void*)(lds_dst), 16, 0, 0);
}

__device__ __forceinline__ uint32_t pack2(float a, float b) {
    uint16_t ua = __builtin_bit_cast(uint16_t, (__bf16)a);
    uint16_t ub = __builtin_bit_cast(uint16_t, (__bf16)b);
    return (uint32_t)ua | ((uint32_t)ub << 16);
}

__device__ __forceinline__ bf16x8 ldv(const void* p) {
    return *reinterpret_cast<const bf16x8*>(p);
}

// XCD-chunked bijective block swizzle: hardware id H runs on XCD H%8; give each
// XCD a CONTIGUOUS chunk of logical ids so panel reuse is L2-local. Requires n%8==0.
__device__ __forceinline__ int xcd_swz(int lid, int n) {
    return (lid & 7) * (n >> 3) + (lid >> 3);
}

// ---------- fused fp32 -> bf16 convert (all 4 weights, one launch) ----------
__global__ __launch_bounds__(256) void cvt4_kernel(const float* __restrict__ s0,
                                                   const float* __restrict__ s1,
                                                   const float* __restrict__ s2,
                                                   const float* __restrict__ s3,
                                                   __bf16* __restrict__ d0,
                                                   __bf16* __restrict__ d1,
                                                   __bf16* __restrict__ d2,
                                                   __bf16* __restrict__ d3) {
    int b = blockIdx.x;
    const float* s; __bf16* d; int off;
    if (b < 3072)       { s = s0; d = d0; off = b; }
    else if (b < 4096)  { s = s1; d = d1; off = b - 3072; }
    else if (b < 12288) { s = s2; d = d2; off = b - 4096; }
    else                { s = s3; d = d3; off = b - 12288; }
    int i = off * 256 + threadIdx.x;
    float4 v = reinterpret_cast<const float4*>(s)[i];
    bf16x4 o;
    o[0] = (__bf16)v.x; o[1] = (__bf16)v.y; o[2] = (__bf16)v.z; o[3] = (__bf16)v.w;
    reinterpret_cast<bf16x4*>(d)[i] = o;
}

// ---------- RMSNorm (row = 1024 fp32) -> bf16 ----------
__global__ __launch_bounds__(256) void rmsnorm_kernel(const float* __restrict__ x,
                                                      const float* __restrict__ g,
                                                      __bf16* __restrict__ out) {
    const int row = blockIdx.x;
    const int t = threadIdx.x;
    float4 v = reinterpret_cast<const float4*>(x + (size_t)row * 1024)[t];
    float ss = v.x * v.x + v.y * v.y + v.z * v.z + v.w * v.w;
#pragma unroll
    for (int m = 1; m < 64; m <<= 1) ss += __shfl_xor(ss, m);
    __shared__ float sred[4];
    if ((t & 63) == 0) sred[t >> 6] = ss;
    __syncthreads();
    float tot = sred[0] + sred[1] + sred[2] + sred[3];
    float rs = rsqrtf(tot * (1.0f / 1024.0f) + 1.1920928955078125e-07f);
    float4 gv = reinterpret_cast<const float4*>(g)[t];
    bf16x4 o;
    o[0] = (__bf16)(v.x * rs * gv.x);
    o[1] = (__bf16)(v.y * rs * gv.y);
    o[2] = (__bf16)(v.z * rs * gv.z);
    o[3] = (__bf16)(v.w * rs * gv.w);
    *reinterpret_cast<bf16x4*>(out + (size_t)row * 1024 + t * 4) = o;
}

// ---------- 8-phase NT GEMM: C[m,n] = sum_k A[m,k]*B[n,k] ----------
// BM=BN=256, BK=64; 512 thr = 8 waves (2Mx4N); per-wave 128x64; 16x16x32 MFMA.
// MODE 0: out bf16. MODE 2: FFN1+SwiGLU fused.
template <int MODE>
__global__ __launch_bounds__(512, 2) void gemm_8p(const __bf16* __restrict__ A, int lda,
                                                  const __bf16* __restrict__ B, int ldb,
                                                  __bf16* __restrict__ outb,
                                                  int K, int ldo) {
    __shared__ __attribute__((aligned(16))) __bf16 Sl[8][256 * 32];
    const int t = threadIdx.x;
    const int lane = t & 63;
    const int wid = t >> 6;
    const int l15 = lane & 15;
    const int g4 = lane >> 4;
    const int nwg = gridDim.x * gridDim.y;
    const int sid = xcd_swz(blockIdx.x + blockIdx.y * gridDim.x, nwg);
    const int bm = sid % gridDim.x, bn = sid / gridDim.x;
    const int wm = (wid >> 2) * 128;
    const int wn = (wid & 3) * 64;

    const __bf16 *pa[2], *pb[2];
#pragma unroll
    for (int i = 0; i < 2; ++i) {
        int L = i * 512 + t, r = L >> 2, c = (L & 3) ^ ((r >> 1) & 3);
        pa[i] = A + (size_t)(bm * 256 + r) * lda + c * 8;
        int rb = bn * 256 + r;
        int srow = (MODE == 2) ? ((rb >> 1) + ((rb & 1) << 12)) : rb;
        pb[i] = B + (size_t)srow * ldb + c * 8;
    }
    auto stageA = [&](int slot) {
#pragma unroll
        for (int i = 0; i < 2; ++i) {
            gload_lds16(pa[i], &Sl[slot][(i * 512 + t) * 8]);
            pa[i] += 32;
        }
    };
    auto stageB = [&](int slot) {
#pragma unroll
        for (int i = 0; i < 2; ++i) {
            gload_lds16(pb[i], &Sl[slot][(i * 512 + t) * 8]);
            pb[i] += 32;
        }
    };

    int aoff[8], boff[4];
#pragma unroll
    for (int m = 0; m < 8; ++m) {
        int r = wm + m * 16 + l15;
        aoff[m] = r * 64 + ((g4 ^ ((r >> 1) & 3)) * 16);
    }
#pragma unroll
    for (int n = 0; n < 4; ++n) {
        int r = wn + n * 16 + l15;
        boff[n] = r * 64 + ((g4 ^ ((r >> 1) & 3)) * 16);
    }

    f32x4 acc[8][4] = {};
    const int NT = K >> 6;

    stageA(0); stageB(1); stageA(2); stageB(3); stageA(4); stageB(5);
    asm volatile("s_waitcnt vmcnt(4)" ::: "memory");
    __builtin_amdgcn_s_barrier();

    for (int tt = 0; tt < NT; ++tt) {
        const int q = (tt & 1) * 4, nq = q ^ 4;
        const char* Alo = (const char*)&Sl[q + 0][0];
        const char* Blo = (const char*)&Sl[q + 1][0];
        const char* Ahi = (const char*)&Sl[q + 2][0];
        const char* Bhi = (const char*)&Sl[q + 3][0];
        bf16x8 af[4], bf[4];

#pragma unroll
        for (int m = 0; m < 4; ++m) af[m] = ldv(Alo + aoff[m]);
#pragma unroll
        for (int n = 0; n < 4; ++n) bf[n] = ldv(Blo + boff[n]);
        if (tt + 1 < NT) stageA(nq + 2);
        __builtin_amdgcn_s_barrier();
        __builtin_amdgcn_s_setprio(1);
#pragma unroll
        for (int m = 0; m < 4; ++m)
#pragma unroll
            for (int n = 0; n < 4; ++n)
                acc[m][n] = MFMA_BF16(af[m], bf[n], acc[m][n]);
        __builtin_amdgcn_s_setprio(0);
        __builtin_amdgcn_s_barrier();

#pragma unroll
        for (int m = 0; m < 4; ++m) af[m] = ldv(Alo + aoff[4 + m]);
        if (tt + 1 < NT) stageB(nq + 3);
        __builtin_amdgcn_s_barrier();
        __builtin_amdgcn_s_setprio(1);
#pragma unroll
        for (int m = 0; m < 4; ++m)
#pragma unroll
            for (int n = 0; n < 4; ++n)
                acc[4 + m][n] = MFMA_BF16(af[m], bf[n], acc[4 + m][n]);
        __builtin_amdgcn_s_setprio(0);
        __builtin_amdgcn_s_barrier();

#pragma unroll
        for (int m = 0; m < 4; ++m) af[m] = ldv(Ahi + aoff[m]);
#pragma unroll
        for (int n = 0; n < 4; ++n) bf[n] = ldv(Bhi + boff[n]);
        if (tt + 2 < NT) stageA(q + 0);
        __builtin_amdgcn_s_barrier();
        __builtin_amdgcn_s_setprio(1);
#pragma unroll
        for (int m = 0; m < 4; ++m)
#pragma unroll
            for (int n = 0; n < 4; ++n)
                acc[m][n] = MFMA_BF16(af[m], bf[n], acc[m][n]);
        __builtin_amdgcn_s_setprio(0);
        __builtin_amdgcn_s_barrier();

#pragma unroll
        for (int m = 0; m < 4; ++m) af[m] = ldv(Ahi + aoff[4 + m]);
        if (tt + 2 < NT) stageB(q + 1);
        __builtin_amdgcn_s_barrier();
        __builtin_amdgcn_s_setprio(1);
#pragma unroll
        for (int m = 0; m < 4; ++m)
#pragma unroll
            for (int n = 0; n < 4; ++n)
                acc[4 + m][n] = MFMA_BF16(af[m], bf[n], acc[4 + m][n]);
        __builtin_amdgcn_s_setprio(0);
        if (tt + 2 < NT) {
            asm volatile("s_waitcnt vmcnt(4)" ::: "memory");
        } else {
            asm volatile("s_waitcnt vmcnt(0)" ::: "memory");
        }
        __builtin_amdgcn_s_barrier();
    }

    const int row0 = bm * 256 + wm + (g4 << 2);
    const int col0 = bn * 256 + wn + l15;
#pragma unroll
    for (int m = 0; m < 8; ++m)
#pragma unroll
        for (int n = 0; n < 4; ++n)
#pragma unroll
            for (int r2 = 0; r2 < 4; ++r2) {
                int row = row0 + m * 16 + r2;
                int col = col0 + n * 16;
                float v = acc[m][n][r2];
                if (MODE == 0) {
                    outb[(size_t)row * ldo + col] = (__bf16)v;
                } else {
                    float pv = __shfl_xor(v, 1);
                    if (!(l15 & 1)) {
                        float sg = v / (1.0f + __expf(-v));
                        outb[(size_t)row * ldo + (col >> 1)] = (__bf16)(sg * pv);
                    }
                }
            }
}

// ---------- NT GEMM (small-N path) ----------
// tile 128 x (NB*32), BK=64, 4 waves (2x2). MODE 0: bf16 out. MODE 1: f32 = acc+resid.
template <int MODE, int NB>
__global__ __launch_bounds__(256) void gemm_nt(const __bf16* __restrict__ A, int lda,
                                               const __bf16* __restrict__ B, int ldb,
                                               __bf16* __restrict__ outb,
                                               float* __restrict__ outf,
                                               const float* __restrict__ resid,
                                               int K, int ldo) {
    constexpr int BN = NB * 32;
    __shared__ __attribute__((aligned(16))) __bf16 As[128 * 64];
    __shared__ __attribute__((aligned(16))) __bf16 Bs[BN * 64];
    const int t = threadIdx.x;
    const int lane = t & 63;
    const int wid = t >> 6;
    const int nwg = gridDim.x * gridDim.y;
    const int sid = xcd_swz(blockIdx.x + blockIdx.y * gridDim.x, nwg);
    const int bm = sid % gridDim.x, bn = sid / gridDim.x;
    const int wm = (wid >> 1) * 64, wn = (wid & 1) * (NB * 16);
    f32x4 acc[4][NB] = {};

    for (int kt = 0; kt < K; kt += 64) {
        __syncthreads();
#pragma unroll
        for (int i = 0; i < 4; ++i) {
            int L = i * 256 + t;
            int r = L >> 3, s = L & 7;
            int c = s ^ (r & 7);
            gload_lds16(A + (size_t)(bm * 128 + r) * lda + kt + c * 8, As + L * 8);
        }
#pragma unroll
        for (int i = 0; i < NB; ++i) {
            int L = i * 256 + t;
            int r = L >> 3, s = L & 7;
            int c = s ^ (r & 7);
            int rb = bn * BN + r;
            gload_lds16(B + (size_t)rb * ldb + kt + c * 8, Bs + L * 8);
        }
        __syncthreads();
#pragma unroll
        for (int ks = 0; ks < 2; ++ks) {
            bf16x8 af[4], bfr[NB];
#pragma unroll
            for (int mi = 0; mi < 4; ++mi) {
                int r = wm + mi * 16 + (lane & 15);
                int slot = (ks * 4 + (lane >> 4)) ^ (r & 7);
                af[mi] = *reinterpret_cast<const bf16x8*>(As + r * 64 + slot * 8);
            }
#pragma unroll
            for (int ni = 0; ni < NB; ++ni) {
                int r = wn + ni * 16 + (lane & 15);
                int slot = (ks * 4 + (lane >> 4)) ^ (r & 7);
                bfr[ni] = *reinterpret_cast<const bf16x8*>(Bs + r * 64 + slot * 8);
            }
            __builtin_amdgcn_s_setprio(1);
#pragma unroll
            for (int mi = 0; mi < 4; ++mi)
#pragma unroll
                for (int ni = 0; ni < NB; ++ni)
                    acc[mi][ni] = MFMA_BF16(af[mi], bfr[ni], acc[mi][ni]);
            __builtin_amdgcn_s_setprio(0);
        }
    }
    const int row0 = bm * 128 + wm + ((lane >> 4) << 2);
    const int col0 = bn * BN + wn + (lane & 15);
#pragma unroll
    for (int mi = 0; mi < 4; ++mi)
#pragma unroll
        for (int ni = 0; ni < NB; ++ni)
#pragma unroll
            for (int r2 = 0; r2 < 4; ++r2) {
                int row = row0 + mi * 16 + r2;
                int col = col0 + ni * 16;
                float v = acc[mi][ni][r2];
                if (MODE == 0) {
                    outb[(size_t)row * ldo + col] = (__bf16)v;
                } else {
                    size_t idx = (size_t)row * ldo + col;
                    outf[idx] = v + resid[idx];
                }
            }
}

// ---------- V transpose: qkv V block [n][hd] -> vt [bh][hd][n] ----------
__global__ __launch_bounds__(256) void vtrans_kernel(const __bf16* __restrict__ qkv,
                                                     __bf16* __restrict__ vt) {
    __shared__ __bf16 T[64][68];
    const int t = threadIdx.x;
    const int bh = blockIdx.y, b = bh >> 4, h = bh & 15;
    const int n0 = blockIdx.x * 64;
    const __bf16* vp = qkv + (size_t)b * 2048 * 3072 + 2048 + h * 64;
#pragma unroll
    for (int i = 0; i < 2; ++i) {
        int r = i * 32 + (t >> 3), c = t & 7;
        bf16x8 v = *reinterpret_cast<const bf16x8*>(vp + (size_t)(n0 + r) * 3072 + c * 8);
#pragma unroll
        for (int j = 0; j < 8; ++j) T[c * 8 + j][r] = v[j];
    }
    __syncthreads();
#pragma unroll
    for (int i = 0; i < 2; ++i) {
        int hd = i * 32 + (t >> 3), c = t & 7;
        bf16x8 v;
#pragma unroll
        for (int j = 0; j < 8; ++j) v[j] = T[hd][c * 8 + j];
        *reinterpret_cast<bf16x8*>(vt + ((size_t)bh * 64 + hd) * 2048 + n0 + c * 8) = v;
    }
}

// ---------- flash attention v3 + setprio + XCD swizzle ----------
__global__ __launch_bounds__(256) void attn_kernel(const __bf16* __restrict__ qkv,
                                                   const __bf16* __restrict__ vt,
                                                   __bf16* __restrict__ o) {
    __shared__ __attribute__((aligned(16))) __bf16 Ks[2][128 * 64];
    __shared__ __attribute__((aligned(16))) __bf16 Vs[2][64 * 128];
    const int t = threadIdx.x;
    const int lane = t & 63;
    const int w = t >> 6;
    const int hi = lane >> 5;
    const int l31 = lane & 31;
    const int nwg = gridDim.x * gridDim.y;
    const int sid = xcd_swz(blockIdx.x + blockIdx.y * gridDim.x, nwg);
    const int qb = sid % gridDim.x;        // q-tile
    const int bh = sid / gridDim.x;        // batch*head
    const int b = bh >> 4, h = bh & 15;
    const __bf16* qp = qkv + (size_t)b * 2048 * 3072 + h * 64;
    const __bf16* kp = qp + 1024;
    const __bf16* vtp = vt + (size_t)bh * 64 * 2048;
    const int q0 = qb * 128 + w * 32;

    const float SC = 0.18033688011112042f;
    bf16x8 qf[4];
#pragma unroll
    for (int s = 0; s < 4; ++s) {
        bf16x8 raw = *reinterpret_cast<const bf16x8*>(
            qp + (size_t)(q0 + l31) * 3072 + s * 16 + hi * 8);
        bf16x8 sc;
#pragma unroll
        for (int j = 0; j < 8; ++j) sc[j] = (__bf16)((float)raw[j] * SC);
        qf[s] = sc;
    }

    f32x16 oa[2] = {};
    float m_run = -INFINITY, l_run = 0.0f;

    auto stage = [&](int buf, int kt) {
#pragma unroll
        for (int i = 0; i < 4; ++i) {
            int L = i * 256 + t;
            int r = L >> 3, s = L & 7;
            int c = s ^ (r & 7);
            gload_lds16(kp + (size_t)(kt + r) * 3072 + c * 8, &Ks[buf][L * 8]);
        }
#pragma unroll
        for (int i = 0; i < 4; ++i) {
            int L = i * 256 + t;
            int r = L >> 4, s = L & 15;
            int c = s ^ (r & 15);
            gload_lds16(vtp + (size_t)r * 2048 + kt + c * 8, &Vs[buf][L * 8]);
        }
    };
    stage(0, 0);
    __syncthreads();

    for (int kt = 0; kt < 2048; kt += 128) {
        const int buf = (kt >> 7) & 1;
        if (kt + 128 < 2048) stage(buf ^ 1, kt + 128);

#pragma unroll
        for (int h2 = 0; h2 < 2; ++h2) {
            f32x16 st[2] = {};
            __builtin_amdgcn_s_setprio(1);
#pragma unroll
            for (int s = 0; s < 4; ++s) {
#pragma unroll
                for (int mb = 0; mb < 2; ++mb) {
                    int r = h2 * 64 + mb * 32 + l31;
                    int sl = (s * 2 + hi) ^ (r & 7);
                    bf16x8 kf = *reinterpret_cast<const bf16x8*>(&Ks[buf][r * 64 + sl * 8]);
                    st[mb] = MFMA32(kf, qf[s], st[mb]);
                }
            }
            __builtin_amdgcn_s_setprio(0);
            float mt = -INFINITY;
#pragma unroll
            for (int mb = 0; mb < 2; ++mb)
#pragma unroll
                for (int r = 0; r < 16; ++r) mt = fmaxf(mt, st[mb][r]);
            mt = fmaxf(mt, __shfl_xor(mt, 32));
            if (__any(mt > m_run + 8.0f)) {
                float m_new = fmaxf(m_run, mt);
                float alpha = exp2f(m_run - m_new);
#pragma unroll
                for (int r = 0; r < 16; ++r) {
                    float av = __shfl(alpha, (r & 3) + 8 * (r >> 2) + 4 * hi);
                    oa[0][r] *= av;
                    oa[1][r] *= av;
                }
                l_run *= alpha;
                m_run = m_new;
            }
            float ps = 0.0f;
#pragma unroll
            for (int mb = 0; mb < 2; ++mb)
#pragma unroll
                for (int r = 0; r < 16; ++r) {
                    float p = exp2f(st[mb][r] - m_run);
                    st[mb][r] = p;
                    ps += p;
                }
            ps += __shfl_xor(ps, 32);
            l_run += ps;

            uint32_t pk[16];
#pragma unroll
            for (int mb = 0; mb < 2; ++mb)
#pragma unroll
                for (int i2 = 0; i2 < 8; ++i2)
                    pk[mb * 8 + i2] = pack2(st[mb][2 * i2], st[mb][2 * i2 + 1]);

            __builtin_amdgcn_s_setprio(1);
#pragma unroll
            for (int s2 = 0; s2 < 4; ++s2) {
                const int I0 = (s2 >> 1) * 8 + (s2 & 1) * 4;
                u32x2 w02 = __builtin_amdgcn_permlane32_swap(pk[I0], pk[I0 + 2], false, false);
                u32x2 w13 = __builtin_amdgcn_permlane32_swap(pk[I0 + 1], pk[I0 + 3], false, false);
                u32x4 fv;
                fv[0] = w02[0]; fv[1] = w13[0]; fv[2] = w02[1]; fv[3] = w13[1];
                bf16x8 pa = __builtin_bit_cast(bf16x8, fv);
#pragma unroll
                for (int nb = 0; nb < 2; ++nb) {
                    int rv = nb * 32 + l31;
                    int ch = h2 * 8 + s2 * 2 + hi;
                    int sl = ch ^ (rv & 15);
                    bf16x8 vf = *reinterpret_cast<const bf16x8*>(&Vs[buf][rv * 128 + sl * 8]);
                    oa[nb] = MFMA32(pa, vf, oa[nb]);
                }
            }
            __builtin_amdgcn_s_setprio(0);
        }
        __syncthreads();
    }

#pragma unroll
    for (int r = 0; r < 16; ++r) {
        int crow = (r & 3) + 8 * (r >> 2) + 4 * hi;
        float lv = __shfl(l_run, crow);
        float inv = 1.0f / lv;
        int row = q0 + crow;
        size_t base = ((size_t)b * 2048 + row) * 1024 + h * 64 + l31;
        o[base]      = (__bf16)(oa[0][r] * inv);
        o[base + 32] = (__bf16)(oa[1][r] * inv);
    }
}

// ---------- launch ----------
extern "C" void kernel_launch(void* const* d_in, const int* in_sizes, int n_in,
                              void* d_out, int out_size, void* d_ws, size_t ws_size,
                              hipStream_t stream) {
    const float* x      = (const float*)d_in[0];
    const float* w_qkv  = (const float*)d_in[3];
    const float* w_o    = (const float*)d_in[4];
    const float* w1     = (const float*)d_in[5];
    const float* w2     = (const float*)d_in[6];
    const float* g_attn = (const float*)d_in[7];
    const float* g_ff   = (const float*)d_in[8];
    float* out = (float*)d_out;

    char* ws = (char*)d_ws;
    size_t off = 0;
    auto alloc = [&](size_t bytes) -> void* {
        void* p = ws + off;
        off += (bytes + 255) & ~(size_t)255;
        return p;
    };
    __bf16* wqkv_b = (__bf16*)alloc((size_t)3072 * 1024 * 2);
    __bf16* wo_b   = (__bf16*)alloc((size_t)1024 * 1024 * 2);
    __bf16* w1_b   = (__bf16*)alloc((size_t)8192 * 1024 * 2);
    __bf16* w2_b   = (__bf16*)alloc((size_t)1024 * 4096 * 2);
    __bf16* h_b    = (__bf16*)alloc((size_t)4096 * 1024 * 2);
    __bf16* qkv_b  = (__bf16*)alloc((size_t)4096 * 3072 * 2);
    __bf16* o_b    = (__bf16*)alloc((size_t)4096 * 1024 * 2);
    float*  x2     = (float*)alloc((size_t)4096 * 1024 * 4);
    __bf16* vt_b   = (__bf16*)alloc((size_t)32 * 64 * 2048 * 2);
    __bf16* act_b  = qkv_b;  // alias: act over [qkv|o] (dead after o-proj)

    cvt4_kernel<<<16384, 256, 0, stream>>>(w_qkv, w_o, w1, w2,
                                           wqkv_b, wo_b, w1_b, w2_b);

    rmsnorm_kernel<<<4096, 256, 0, stream>>>(x, g_attn, h_b);
    // qkv: 128x128 tiles, 768 blocks (~3/CU)
    gemm_nt<0, 4><<<dim3(32, 24), 256, 0, stream>>>(h_b, 1024, wqkv_b, 1024,
                                                    qkv_b, nullptr, nullptr, 1024, 3072);
    vtrans_kernel<<<dim3(32, 32), 256, 0, stream>>>(qkv_b, vt_b);
    attn_kernel<<<dim3(16, 32), 256, 0, stream>>>(qkv_b, vt_b, o_b);
    gemm_nt<1, 2><<<dim3(32, 16), 256, 0, stream>>>(o_b, 1024, wo_b, 1024,
                                                    nullptr, x2, x, 1024, 1024);
    rmsnorm_kernel<<<4096, 256, 0, stream>>>(x2, g_ff, h_b);
    // ffn1: 8-phase + fused SwiGLU + XCD swizzle
    gemm_8p<2><<<dim3(16, 32), 512, 0, stream>>>(h_b, 1024, w1_b, 1024,
                                                 act_b, 1024, 4096);
    gemm_nt<1, 2><<<dim3(32, 16), 256, 0, stream>>>(act_b, 4096, w2_b, 4096,
                                                    nullptr, out, x2, 4096, 1024);
}